// Round 4
// baseline (352.473 us; speedup 1.0000x reference)
//
#include <hip/hip_runtime.h>

typedef __bf16 bf16;
typedef float f32x4 __attribute__((ext_vector_type(4)));
typedef bf16 bf16x8 __attribute__((ext_vector_type(8)));
typedef bf16 bf16x4 __attribute__((ext_vector_type(4)));

#define NB 4
#define NQ 384
#define NK 384
#define DE 64
#define DQI 256
#define DFF 256
#define DMSG 64
#define DOUT 64

// ws layout (bytes): AqT/AkT are [B][256 c][384 n] f32 (transposed for coalesced bias staging)
#define WS_AQT 0
#define WS_AKT 1572864
#define WS_W1T 3145728
#define WS_W2T 3211264

__global__ __launch_bounds__(256) void prep_kernel(
    const float* __restrict__ q_inv, const float* __restrict__ k_inv,
    const float* __restrict__ Wq, const float* __restrict__ bq,
    const float* __restrict__ Wk, const float* __restrict__ bk,
    const float* __restrict__ W1, const float* __restrict__ b1,
    const float* __restrict__ W2,
    float* __restrict__ AqT, float* __restrict__ AkT,
    bf16* __restrict__ w1t, bf16* __restrict__ w2t)
{
  const int t = threadIdx.x;
  const int bid = blockIdx.x;
  if (bid < 2 * NB * 24) {
    // msg projection + A = msg @ W1[rows] (+b1 on Q side), written TRANSPOSED: A_T[b][c][n]
    const bool isQ = bid < NB * 24;
    const int sub = isQ ? bid : bid - NB * 24;
    const int b = sub / 24, tile = sub % 24;
    const int n0 = tile * 16;
    __shared__ float sInv[16 * 256];
    __shared__ float sMsg[16 * 64];
    const float* inv = isQ ? q_inv : k_inv;
    const float* Wm = isQ ? Wq : Wk;
    const float* bm = isQ ? bq : bk;
#pragma unroll
    for (int r = 0; r < 16; ++r)
      sInv[r * 256 + t] = inv[(b * 384 + n0 + r) * 256 + t];
    __syncthreads();
    {
      const int e = t & 63, rq = t >> 6;
      float acc[4];
#pragma unroll
      for (int rr = 0; rr < 4; ++rr) acc[rr] = bm[e];
      for (int d = 0; d < 256; ++d) {
        float wv = Wm[d * DMSG + e];
#pragma unroll
        for (int rr = 0; rr < 4; ++rr) acc[rr] += sInv[(rq * 4 + rr) * 256 + d] * wv;
      }
#pragma unroll
      for (int rr = 0; rr < 4; ++rr) sMsg[(rq * 4 + rr) * 64 + e] = acc[rr];
    }
    __syncthreads();
    {
      const int c = t;
      const float* w1r = W1 + (isQ ? 0 : DMSG * DFF);
      float acc[16];
#pragma unroll
      for (int n = 0; n < 16; ++n) acc[n] = isQ ? b1[c] : 0.f;
      for (int e = 0; e < 64; ++e) {
        float wv = w1r[e * DFF + c];
#pragma unroll
        for (int n = 0; n < 16; ++n) acc[n] += sMsg[n * 64 + e] * wv;
      }
      float* dst = (isQ ? AqT : AkT) + (b * 256 + c) * 384 + n0;
#pragma unroll
      for (int n = 0; n < 16; ++n) dst[n] = acc[n];
    }
  } else if (bid == 2 * NB * 24) {
    // w1t[cs][k] = bf16(W1[128+k][c(cs)]), row-permuted c
    const int cs = t;
    const int c = ((cs >> 5) << 5) + (((cs >> 4) & 1) << 2) + (((cs >> 2) & 3) << 3) + (cs & 3);
    for (int k8 = 0; k8 < 16; ++k8) {
      bf16x8 v;
#pragma unroll
      for (int j = 0; j < 8; ++j) {
        int k = k8 * 8 + j;
        v[j] = (bf16)W1[(128 + k) * DFF + c];
      }
      *(bf16x8*)&w1t[cs * 128 + k8 * 8] = v;
    }
  } else {
    // w2t[ocol][ks] = bf16(W2[ctrue(ks)][ocol]), K-permuted to match in-register h fragments
    const int ocol = t >> 2;
    const int ksc = t & 3;
    for (int k8 = 0; k8 < 8; ++k8) {
      bf16x8 v;
#pragma unroll
      for (int j = 0; j < 8; ++j) {
        int ks = ksc * 64 + k8 * 8 + j;
        int ct = ((ks >> 5) << 5) + (((ks >> 3) & 3) << 3) + (((ks >> 2) & 1) << 2) + (ks & 3);
        v[j] = (bf16)W2[ct * DOUT + ocol];
      }
      *(bf16x8*)&w2t[ocol * 256 + ksc * 64 + k8 * 8] = v;
    }
  }
}

__global__ __launch_bounds__(256, 2) void pair_kernel(
    const float* __restrict__ q_equi, const float* __restrict__ k_equi,
    const float* __restrict__ AqT, const float* __restrict__ AkT,
    const bf16* __restrict__ w1t, const bf16* __restrict__ w2t,
    const float* __restrict__ b2, float* __restrict__ out)
{
  // 64 KB (XOR-chunk-swizzled W1^T) + 16 KB (fragment-major bias) = 81920 B -> 2 blocks/CU
  __shared__ __align__(16) bf16 sA1[256 * 128];
  __shared__ __align__(16) bf16 sAb[16 * 4 * 16 * 8];

  const int t = threadIdx.x;
  const int bid = blockIdx.x;
  const int b = bid / (24 * 8);
  const int rem = bid % (24 * 8);
  const int qt = rem / 8, ks = rem % 8;
  const int q0 = qt * 16;
  const int k0b = ks * 48;

  const int lane = t & 63;
  const int w = t >> 6;
  const int r16 = lane & 15;
  const int g = lane >> 4;

  // ---------- prologue ----------
  {  // W1^T -> LDS with chunk-XOR swizzle (rows stride 256B would be bank-aligned otherwise)
    const bf16* src = w1t + t * 128;
    bf16* dstrow = sA1 + t * 128;
#pragma unroll
    for (int k8 = 0; k8 < 16; ++k8)
      *(bf16x8*)&dstrow[((k8 ^ (t & 15)) << 3)] = *(const bf16x8*)&src[k8 * 8];
  }
  {  // bias buffer, Q half: fragment-major [ct][g][r16][8], value = Aq[q0+g*8+j][c(cs=t)]
    const int c = ((t >> 5) << 5) + (((t >> 4) & 1) << 2) + (((t >> 2) & 3) << 3) + (t & 3);
    const float* aqp = AqT + (b * 256 + c) * 384 + q0;
    const int ct = t >> 4, rr = t & 15;
#pragma unroll
    for (int gg = 0; gg < 2; ++gg) {
      f32x4 v0 = *(const f32x4*)&aqp[gg * 8];
      f32x4 v1 = *(const f32x4*)&aqp[gg * 8 + 4];
      bf16x8 vv;
#pragma unroll
      for (int j = 0; j < 4; ++j) { vv[j] = (bf16)v0[j]; vv[4 + j] = (bf16)v1[j]; }
      *(bf16x8*)&sAb[((ct * 4 + gg) * 16 + rr) * 8] = vv;
    }
  }
  // one-hot B-fragments for the bias K-slice (synthesized, no LDS)
  bf16x8 b1sel[4];
#pragma unroll
  for (int pt = 0; pt < 4; ++pt) {
#pragma unroll
    for (int j = 0; j < 8; ++j) {
      const int jj = g * 8 + j;
      float v;
      if (g < 2) v = (jj == r16) ? 1.f : 0.f;
      else v = ((jj - 16) == (w * 4 + pt)) ? 1.f : 0.f;
      b1sel[pt][j] = (bf16)v;
    }
  }

  for (int it = 0; it < 3; ++it) {
    const int k0i = k0b + it * 16;
    // ---------- feats: straight into this lane's B-fragments (no LDS) ----------
    bf16x8 b1f[4][4];
    {
      const int qrow = b * NQ + q0 + r16;
      f32x4 qv[3][4];
#pragma unroll
      for (int c = 0; c < 3; ++c) {
        const float* qp = q_equi + (qrow * 3 + c) * DE;
        qv[c][0] = *(const f32x4*)&qp[g * 8];
        qv[c][1] = *(const f32x4*)&qp[g * 8 + 4];
        qv[c][2] = *(const f32x4*)&qp[32 + g * 8];
        qv[c][3] = *(const f32x4*)&qp[32 + g * 8 + 4];
      }
#pragma unroll
      for (int pt = 0; pt < 4; ++pt) {
        const int krow = b * NK + k0i + w * 4 + pt;
        f32x4 dt[4], s2[4];
#pragma unroll
        for (int h = 0; h < 4; ++h) { dt[h] = (f32x4){0,0,0,0}; s2[h] = (f32x4){0,0,0,0}; }
#pragma unroll
        for (int c = 0; c < 3; ++c) {
          const float* kp = k_equi + (krow * 3 + c) * DE;
          f32x4 kv0 = *(const f32x4*)&kp[g * 8];
          f32x4 kv1 = *(const f32x4*)&kp[g * 8 + 4];
          f32x4 kv2 = *(const f32x4*)&kp[32 + g * 8];
          f32x4 kv3 = *(const f32x4*)&kp[32 + g * 8 + 4];
          dt[0] += qv[c][0] * kv0; dt[1] += qv[c][1] * kv1;
          dt[2] += qv[c][2] * kv2; dt[3] += qv[c][3] * kv3;
          f32x4 e0 = qv[c][0] - kv0, e1 = qv[c][1] - kv1, e2 = qv[c][2] - kv2, e3 = qv[c][3] - kv3;
          s2[0] += e0 * e0; s2[1] += e1 * e1; s2[2] += e2 * e2; s2[3] += e3 * e3;
        }
        bf16x8 f0, f1, f2, f3;
#pragma unroll
        for (int j = 0; j < 4; ++j) {
          f0[j] = (bf16)dt[0][j]; f0[4 + j] = (bf16)dt[1][j];
          f1[j] = (bf16)dt[2][j]; f1[4 + j] = (bf16)dt[3][j];
          f2[j] = (bf16)__builtin_amdgcn_sqrtf(s2[0][j]);
          f2[4 + j] = (bf16)__builtin_amdgcn_sqrtf(s2[1][j]);
          f3[j] = (bf16)__builtin_amdgcn_sqrtf(s2[2][j]);
          f3[4 + j] = (bf16)__builtin_amdgcn_sqrtf(s2[3][j]);
        }
        b1f[pt][0] = f0; b1f[pt][1] = f1; b1f[pt][2] = f2; b1f[pt][3] = f3;
      }
    }
    {  // bias buffer, K half for this k-tile: value = Ak[k0i+(g-2)*8+j][c(cs=t)]
      const int c = ((t >> 5) << 5) + (((t >> 4) & 1) << 2) + (((t >> 2) & 3) << 3) + (t & 3);
      const float* akp = AkT + (b * 256 + c) * 384 + k0i;
      const int ct = t >> 4, rr = t & 15;
#pragma unroll
      for (int gg = 2; gg < 4; ++gg) {
        f32x4 v0 = *(const f32x4*)&akp[(gg - 2) * 8];
        f32x4 v1 = *(const f32x4*)&akp[(gg - 2) * 8 + 4];
        bf16x8 vv;
#pragma unroll
        for (int j = 0; j < 4; ++j) { vv[j] = (bf16)v0[j]; vv[4 + j] = (bf16)v1[j]; }
        *(bf16x8*)&sAb[((ct * 4 + gg) * 16 + rr) * 8] = vv;
      }
    }
    __syncthreads();
    // ---------- GEMM phase ----------
    {
      f32x4 D2[4][4];
#pragma unroll
      for (int ot = 0; ot < 4; ++ot)
#pragma unroll
        for (int pt = 0; pt < 4; ++pt)
          D2[ot][pt] = (f32x4){0.f, 0.f, 0.f, 0.f};

#pragma unroll
      for (int kk2 = 0; kk2 < 8; ++kk2) {
        const int ctE = kk2 * 2, ctO = kk2 * 2 + 1;
        f32x4 dE[4], dO[4];
#pragma unroll
        for (int pt = 0; pt < 4; ++pt) {
          dE[pt] = (f32x4){0.f, 0.f, 0.f, 0.f};
          dO[pt] = (f32x4){0.f, 0.f, 0.f, 0.f};
        }
#pragma unroll
        for (int kk = 0; kk < 4; ++kk) {
          bf16x8 aE = *(const bf16x8*)&sA1[(ctE * 16 + r16) * 128 + (((kk * 4 + g) ^ r16) << 3)];
#pragma unroll
          for (int pt = 0; pt < 4; ++pt)
            dE[pt] = __builtin_amdgcn_mfma_f32_16x16x32_bf16(aE, b1f[pt][kk], dE[pt], 0, 0, 0);
          bf16x8 aO = *(const bf16x8*)&sA1[(ctO * 16 + r16) * 128 + (((kk * 4 + g) ^ r16) << 3)];
#pragma unroll
          for (int pt = 0; pt < 4; ++pt)
            dO[pt] = __builtin_amdgcn_mfma_f32_16x16x32_bf16(aO, b1f[pt][kk], dO[pt], 0, 0, 0);
        }
        {  // bias one-hot K-slice
          bf16x8 aBE = *(const bf16x8*)&sAb[((ctE * 4 + g) * 16 + r16) * 8];
          bf16x8 aBO = *(const bf16x8*)&sAb[((ctO * 4 + g) * 16 + r16) * 8];
#pragma unroll
          for (int pt = 0; pt < 4; ++pt) {
            dE[pt] = __builtin_amdgcn_mfma_f32_16x16x32_bf16(aBE, b1sel[pt], dE[pt], 0, 0, 0);
            dO[pt] = __builtin_amdgcn_mfma_f32_16x16x32_bf16(aBO, b1sel[pt], dO[pt], 0, 0, 0);
          }
        }
        bf16x8 a2[4];
#pragma unroll
        for (int ot = 0; ot < 4; ++ot)
          a2[ot] = *(const bf16x8*)&w2t[(ot * 16 + r16) * 256 + kk2 * 32 + g * 8];
#pragma unroll
        for (int pt = 0; pt < 4; ++pt) {
          bf16x8 b2f;  // silu(z) in-register -> GEMM2 B-fragment
#pragma unroll
          for (int r = 0; r < 4; ++r) {
            float zE = dE[pt][r];
            float sE = zE * __builtin_amdgcn_rcpf(1.f + __builtin_amdgcn_exp2f(zE * -1.44269504f));
            b2f[r] = (bf16)sE;
            float zO = dO[pt][r];
            float sO = zO * __builtin_amdgcn_rcpf(1.f + __builtin_amdgcn_exp2f(zO * -1.44269504f));
            b2f[4 + r] = (bf16)sO;
          }
#pragma unroll
          for (int ot = 0; ot < 4; ++ot)
            D2[ot][pt] = __builtin_amdgcn_mfma_f32_16x16x32_bf16(a2[ot], b2f, D2[ot][pt], 0, 0, 0);
        }
      }
      // epilogue: out^T fragments; lane holds 4 consecutive ocol for its (q,k)
      f32x4 b2v[4];
#pragma unroll
      for (int ot = 0; ot < 4; ++ot)
        b2v[ot] = *(const f32x4*)&b2[ot * 16 + g * 4];
#pragma unroll
      for (int pt = 0; pt < 4; ++pt) {
        const int kg = k0i + w * 4 + pt;
        float* op = out + ((b * NQ + q0 + r16) * NK + kg) * 64 + g * 4;
#pragma unroll
        for (int ot = 0; ot < 4; ++ot) {
          f32x4 v = D2[ot][pt] + b2v[ot];
          *(f32x4*)&op[ot * 16] = v;
        }
      }
    }
    __syncthreads();
  }
}

extern "C" void kernel_launch(void* const* d_in, const int* in_sizes, int n_in,
                              void* d_out, int out_size, void* d_ws, size_t ws_size,
                              hipStream_t stream) {
  const float* q_equi = (const float*)d_in[0];
  const float* q_inv = (const float*)d_in[1];
  const float* k_equi = (const float*)d_in[2];
  const float* k_inv = (const float*)d_in[3];
  const float* Wq = (const float*)d_in[4];
  const float* bq = (const float*)d_in[5];
  const float* Wk = (const float*)d_in[6];
  const float* bk = (const float*)d_in[7];
  const float* W1 = (const float*)d_in[8];
  const float* b1 = (const float*)d_in[9];
  const float* W2 = (const float*)d_in[10];
  const float* b2 = (const float*)d_in[11];
  char* ws = (char*)d_ws;
  float* AqT = (float*)(ws + WS_AQT);
  float* AkT = (float*)(ws + WS_AKT);
  bf16* w1t = (bf16*)(ws + WS_W1T);
  bf16* w2t = (bf16*)(ws + WS_W2T);
  float* out = (float*)d_out;

  prep_kernel<<<2 * NB * 24 + 2, 256, 0, stream>>>(q_inv, k_inv, Wq, bq, Wk, bk, W1, b1, W2,
                                                   AqT, AkT, w1t, w2t);
  pair_kernel<<<NB * 24 * 8, 256, 0, stream>>>(q_equi, k_equi, AqT, AkT, w1t, w2t, b2, out);
}

// Round 5
// 340.527 us; speedup vs baseline: 1.0351x; 1.0351x over previous
//
#include <hip/hip_runtime.h>

typedef __bf16 bf16;
typedef float f32x4 __attribute__((ext_vector_type(4)));
typedef bf16 bf16x8 __attribute__((ext_vector_type(8)));
typedef bf16 bf16x4 __attribute__((ext_vector_type(4)));

#define NB 4
#define NQ 384
#define NK 384
#define DE 64
#define DQI 256
#define DFF 256
#define DMSG 64
#define DOUT 64

// ws layout (bytes): Abq/Abk are bf16 fragment-ready tiles [b][tile24][ct16][gg2][rr16][8]
#define WS_ABQ 0
#define WS_ABK 786432
#define WS_W1T 1572864
#define WS_W2T 1638400

__global__ __launch_bounds__(256) void prep_kernel(
    const float* __restrict__ q_inv, const float* __restrict__ k_inv,
    const float* __restrict__ Wq, const float* __restrict__ bq,
    const float* __restrict__ Wk, const float* __restrict__ bk,
    const float* __restrict__ W1, const float* __restrict__ b1,
    const float* __restrict__ W2,
    bf16* __restrict__ Abq, bf16* __restrict__ Abk,
    bf16* __restrict__ w1t, bf16* __restrict__ w2t)
{
  const int t = threadIdx.x;
  const int bid = blockIdx.x;
  if (bid < 2 * NB * 24) {
    // msg projection + A = msg @ W1[rows] (+b1 on Q side), emitted fragment-ready bf16
    const bool isQ = bid < NB * 24;
    const int sub = isQ ? bid : bid - NB * 24;
    const int b = sub / 24, tile = sub % 24;
    const int n0 = tile * 16;
    __shared__ float sInv[16 * 256];
    __shared__ float sMsg[16 * 64];
    const float* inv = isQ ? q_inv : k_inv;
    const float* Wm = isQ ? Wq : Wk;
    const float* bm = isQ ? bq : bk;
#pragma unroll
    for (int r = 0; r < 16; ++r)
      sInv[r * 256 + t] = inv[(b * 384 + n0 + r) * 256 + t];
    __syncthreads();
    {
      const int e = t & 63, rq = t >> 6;
      float acc[4];
#pragma unroll
      for (int rr = 0; rr < 4; ++rr) acc[rr] = bm[e];
      for (int d = 0; d < 256; ++d) {
        float wv = Wm[d * DMSG + e];
#pragma unroll
        for (int rr = 0; rr < 4; ++rr) acc[rr] += sInv[(rq * 4 + rr) * 256 + d] * wv;
      }
#pragma unroll
      for (int rr = 0; rr < 4; ++rr) sMsg[(rq * 4 + rr) * 64 + e] = acc[rr];
    }
    __syncthreads();
    {
      const int c = t;
      const float* w1r = W1 + (isQ ? 0 : DMSG * DFF);
      float acc[16];
#pragma unroll
      for (int n = 0; n < 16; ++n) acc[n] = isQ ? b1[c] : 0.f;
      for (int e = 0; e < 64; ++e) {
        float wv = w1r[e * DFF + c];
#pragma unroll
        for (int n = 0; n < 16; ++n) acc[n] += sMsg[n * 64 + e] * wv;
      }
      // fragment-ready store: cs = inverse c-permutation; tile elem [(ct*2+gg)*16+rr][8]
      const int cs = (c & 0xE0) | ((c & 0x18) >> 1) | ((c & 4) << 2) | (c & 3);
      const int ct = cs >> 4, rr = cs & 15;
      bf16* dst = (isQ ? Abq : Abk) + (b * 24 + tile) * 4096;
#pragma unroll
      for (int gg = 0; gg < 2; ++gg) {
        bf16x8 vv;
#pragma unroll
        for (int j = 0; j < 8; ++j) vv[j] = (bf16)acc[gg * 8 + j];
        *(bf16x8*)&dst[((ct * 2 + gg) * 16 + rr) * 8] = vv;
      }
    }
  } else if (bid == 2 * NB * 24) {
    // w1t[cs][k] = bf16(W1[128+k][c(cs)]), row-permuted c
    const int cs = t;
    const int c = ((cs >> 5) << 5) + (((cs >> 4) & 1) << 2) + (((cs >> 2) & 3) << 3) + (cs & 3);
    for (int k8 = 0; k8 < 16; ++k8) {
      bf16x8 v;
#pragma unroll
      for (int j = 0; j < 8; ++j) {
        int k = k8 * 8 + j;
        v[j] = (bf16)W1[(128 + k) * DFF + c];
      }
      *(bf16x8*)&w1t[cs * 128 + k8 * 8] = v;
    }
  } else {
    // w2t[ocol][ks] = bf16(W2[ctrue(ks)][ocol]), K-permuted to match in-register h fragments
    const int ocol = t >> 2;
    const int ksc = t & 3;
    for (int k8 = 0; k8 < 8; ++k8) {
      bf16x8 v;
#pragma unroll
      for (int j = 0; j < 8; ++j) {
        int ks = ksc * 64 + k8 * 8 + j;
        int ct = ((ks >> 5) << 5) + (((ks >> 3) & 3) << 3) + (((ks >> 2) & 1) << 2) + (ks & 3);
        v[j] = (bf16)W2[ct * DOUT + ocol];
      }
      *(bf16x8*)&w2t[ocol * 256 + ksc * 64 + k8 * 8] = v;
    }
  }
}

__global__ __launch_bounds__(256) void pair_kernel(
    const float* __restrict__ q_equi, const float* __restrict__ k_equi,
    const bf16* __restrict__ Abq, const bf16* __restrict__ Abk,
    const bf16* __restrict__ w1t, const bf16* __restrict__ w2t,
    const float* __restrict__ b2, float* __restrict__ out)
{
  // 64 KB (XOR-chunk-swizzled W1^T) + 16 KB (fragment-major bias) = 81920 B -> 2 blocks/CU
  __shared__ __align__(16) bf16 sA1[256 * 128];
  __shared__ __align__(16) bf16 sAb[16 * 4 * 16 * 8];

  const int t = threadIdx.x;
  // XCD-aware bijective swizzle: XCD x (= blockIdx%8) owns 12 contiguous q-tiles of one half-batch
  const int bid0 = blockIdx.x;
  const int l = (bid0 & 7) * 96 + (bid0 >> 3);
  const int b = l / 192;
  const int rem = l % 192;
  const int qt = rem / 8, ks = rem % 8;
  const int q0 = qt * 16;
  const int k0b = ks * 48;

  const int lane = t & 63;
  const int w = t >> 6;
  const int r16 = lane & 15;
  const int g = lane >> 4;
  const int ct = t >> 4, rr = t & 15;

  // ---------- prologue ----------
  {  // W1^T -> LDS with chunk-XOR swizzle (rows stride 256B would be bank-aligned otherwise)
    const bf16* src = w1t + t * 128;
    bf16* dstrow = sA1 + t * 128;
#pragma unroll
    for (int k8 = 0; k8 < 16; ++k8)
      *(bf16x8*)&dstrow[((k8 ^ (t & 15)) << 3)] = *(const bf16x8*)&src[k8 * 8];
  }
  {  // bias buffer Q half: contiguous fragment-ready copy (8 KB)
    const bf16* src = Abq + (b * 24 + qt) * 4096;
#pragma unroll
    for (int gg = 0; gg < 2; ++gg)
      *(bf16x8*)&sAb[((ct * 4 + gg) * 16 + rr) * 8] =
          *(const bf16x8*)&src[((ct * 2 + gg) * 16 + rr) * 8];
  }
  // one-hot B-fragments for the bias K-slice (synthesized, no LDS)
  bf16x8 b1sel[4];
#pragma unroll
  for (int pt = 0; pt < 4; ++pt) {
#pragma unroll
    for (int j = 0; j < 8; ++j) {
      const int jj = g * 8 + j;
      float v;
      if (g < 2) v = (jj == r16) ? 1.f : 0.f;
      else v = ((jj - 16) == (w * 4 + pt)) ? 1.f : 0.f;
      b1sel[pt][j] = (bf16)v;
    }
  }

  for (int it = 0; it < 3; ++it) {
    const int k0i = k0b + it * 16;
    {  // bias buffer K half for this k-tile: contiguous fragment-ready copy (8 KB)
      const bf16* src = Abk + (b * 24 + (k0i >> 4)) * 4096;
#pragma unroll
      for (int gg = 0; gg < 2; ++gg)
        *(bf16x8*)&sAb[((ct * 4 + 2 + gg) * 16 + rr) * 8] =
            *(const bf16x8*)&src[((ct * 2 + gg) * 16 + rr) * 8];
    }
    // ---------- feats: straight into this lane's B-fragments (no LDS) ----------
    bf16x8 b1f[4][4];
    {
      const int qrow = b * NQ + q0 + r16;
      f32x4 qv[3][4];
#pragma unroll
      for (int c = 0; c < 3; ++c) {
        const float* qp = q_equi + (qrow * 3 + c) * DE;
        qv[c][0] = *(const f32x4*)&qp[g * 8];
        qv[c][1] = *(const f32x4*)&qp[g * 8 + 4];
        qv[c][2] = *(const f32x4*)&qp[32 + g * 8];
        qv[c][3] = *(const f32x4*)&qp[32 + g * 8 + 4];
      }
#pragma unroll
      for (int pt = 0; pt < 4; ++pt) {
        const int krow = b * NK + k0i + w * 4 + pt;
        f32x4 dt[4], s2[4];
#pragma unroll
        for (int h = 0; h < 4; ++h) { dt[h] = (f32x4){0,0,0,0}; s2[h] = (f32x4){0,0,0,0}; }
#pragma unroll
        for (int c = 0; c < 3; ++c) {
          const float* kp = k_equi + (krow * 3 + c) * DE;
          f32x4 kv0 = *(const f32x4*)&kp[g * 8];
          f32x4 kv1 = *(const f32x4*)&kp[g * 8 + 4];
          f32x4 kv2 = *(const f32x4*)&kp[32 + g * 8];
          f32x4 kv3 = *(const f32x4*)&kp[32 + g * 8 + 4];
          dt[0] += qv[c][0] * kv0; dt[1] += qv[c][1] * kv1;
          dt[2] += qv[c][2] * kv2; dt[3] += qv[c][3] * kv3;
          f32x4 e0 = qv[c][0] - kv0, e1 = qv[c][1] - kv1, e2 = qv[c][2] - kv2, e3 = qv[c][3] - kv3;
          s2[0] += e0 * e0; s2[1] += e1 * e1; s2[2] += e2 * e2; s2[3] += e3 * e3;
        }
        bf16x8 f0, f1, f2, f3;
#pragma unroll
        for (int j = 0; j < 4; ++j) {
          f0[j] = (bf16)dt[0][j]; f0[4 + j] = (bf16)dt[1][j];
          f1[j] = (bf16)dt[2][j]; f1[4 + j] = (bf16)dt[3][j];
          f2[j] = (bf16)__builtin_amdgcn_sqrtf(s2[0][j]);
          f2[4 + j] = (bf16)__builtin_amdgcn_sqrtf(s2[1][j]);
          f3[j] = (bf16)__builtin_amdgcn_sqrtf(s2[2][j]);
          f3[4 + j] = (bf16)__builtin_amdgcn_sqrtf(s2[3][j]);
        }
        b1f[pt][0] = f0; b1f[pt][1] = f1; b1f[pt][2] = f2; b1f[pt][3] = f3;
      }
    }
    __syncthreads();
    // ---------- GEMM phase ----------
    {
      f32x4 D2[4][4];
#pragma unroll
      for (int ot = 0; ot < 4; ++ot)
#pragma unroll
        for (int pt = 0; pt < 4; ++pt)
          D2[ot][pt] = (f32x4){0.f, 0.f, 0.f, 0.f};

#pragma unroll
      for (int kk2 = 0; kk2 < 8; ++kk2) {
        const int ctE = kk2 * 2, ctO = kk2 * 2 + 1;
        f32x4 dE[4], dO[4];
#pragma unroll
        for (int pt = 0; pt < 4; ++pt) {
          dE[pt] = (f32x4){0.f, 0.f, 0.f, 0.f};
          dO[pt] = (f32x4){0.f, 0.f, 0.f, 0.f};
        }
#pragma unroll
        for (int kk = 0; kk < 4; ++kk) {
          bf16x8 aE = *(const bf16x8*)&sA1[(ctE * 16 + r16) * 128 + (((kk * 4 + g) ^ r16) << 3)];
#pragma unroll
          for (int pt = 0; pt < 4; ++pt)
            dE[pt] = __builtin_amdgcn_mfma_f32_16x16x32_bf16(aE, b1f[pt][kk], dE[pt], 0, 0, 0);
          bf16x8 aO = *(const bf16x8*)&sA1[(ctO * 16 + r16) * 128 + (((kk * 4 + g) ^ r16) << 3)];
#pragma unroll
          for (int pt = 0; pt < 4; ++pt)
            dO[pt] = __builtin_amdgcn_mfma_f32_16x16x32_bf16(aO, b1f[pt][kk], dO[pt], 0, 0, 0);
        }
        {  // bias one-hot K-slice
          bf16x8 aBE = *(const bf16x8*)&sAb[((ctE * 4 + g) * 16 + r16) * 8];
          bf16x8 aBO = *(const bf16x8*)&sAb[((ctO * 4 + g) * 16 + r16) * 8];
#pragma unroll
          for (int pt = 0; pt < 4; ++pt) {
            dE[pt] = __builtin_amdgcn_mfma_f32_16x16x32_bf16(aBE, b1sel[pt], dE[pt], 0, 0, 0);
            dO[pt] = __builtin_amdgcn_mfma_f32_16x16x32_bf16(aBO, b1sel[pt], dO[pt], 0, 0, 0);
          }
        }
        bf16x8 a2[4];
#pragma unroll
        for (int ot = 0; ot < 4; ++ot)
          a2[ot] = *(const bf16x8*)&w2t[(ot * 16 + r16) * 256 + kk2 * 32 + g * 8];
#pragma unroll
        for (int pt = 0; pt < 4; ++pt) {
          bf16x8 b2f;  // silu(z) in-register -> GEMM2 B-fragment
#pragma unroll
          for (int r = 0; r < 4; ++r) {
            float zE = dE[pt][r];
            float sE = zE * __builtin_amdgcn_rcpf(1.f + __builtin_amdgcn_exp2f(zE * -1.44269504f));
            b2f[r] = (bf16)sE;
            float zO = dO[pt][r];
            float sO = zO * __builtin_amdgcn_rcpf(1.f + __builtin_amdgcn_exp2f(zO * -1.44269504f));
            b2f[4 + r] = (bf16)sO;
          }
#pragma unroll
          for (int ot = 0; ot < 4; ++ot)
            D2[ot][pt] = __builtin_amdgcn_mfma_f32_16x16x32_bf16(a2[ot], b2f, D2[ot][pt], 0, 0, 0);
        }
      }
      // epilogue: out^T fragments via non-temporal stores (don't thrash L2)
      f32x4 b2v[4];
#pragma unroll
      for (int ot = 0; ot < 4; ++ot)
        b2v[ot] = *(const f32x4*)&b2[ot * 16 + g * 4];
#pragma unroll
      for (int pt = 0; pt < 4; ++pt) {
        const int kg = k0i + w * 4 + pt;
        float* op = out + ((b * NQ + q0 + r16) * NK + kg) * 64 + g * 4;
#pragma unroll
        for (int ot = 0; ot < 4; ++ot) {
          f32x4 v = D2[ot][pt] + b2v[ot];
          __builtin_nontemporal_store(v, (f32x4*)&op[ot * 16]);
        }
      }
    }
    __syncthreads();
  }
}

extern "C" void kernel_launch(void* const* d_in, const int* in_sizes, int n_in,
                              void* d_out, int out_size, void* d_ws, size_t ws_size,
                              hipStream_t stream) {
  const float* q_equi = (const float*)d_in[0];
  const float* q_inv = (const float*)d_in[1];
  const float* k_equi = (const float*)d_in[2];
  const float* k_inv = (const float*)d_in[3];
  const float* Wq = (const float*)d_in[4];
  const float* bq = (const float*)d_in[5];
  const float* Wk = (const float*)d_in[6];
  const float* bk = (const float*)d_in[7];
  const float* W1 = (const float*)d_in[8];
  const float* b1 = (const float*)d_in[9];
  const float* W2 = (const float*)d_in[10];
  const float* b2 = (const float*)d_in[11];
  char* ws = (char*)d_ws;
  bf16* Abq = (bf16*)(ws + WS_ABQ);
  bf16* Abk = (bf16*)(ws + WS_ABK);
  bf16* w1t = (bf16*)(ws + WS_W1T);
  bf16* w2t = (bf16*)(ws + WS_W2T);
  float* out = (float*)d_out;

  prep_kernel<<<2 * NB * 24 + 2, 256, 0, stream>>>(q_inv, k_inv, Wq, bq, Wk, bk, W1, b1, W2,
                                                   Abq, Abk, w1t, w2t);
  pair_kernel<<<NB * 24 * 8, 256, 0, stream>>>(q_equi, k_equi, Abq, Abk, w1t, w2t, b2, out);
}